// Round 3
// baseline (1191.896 us; speedup 1.0000x reference)
//
#include <hip/hip_runtime.h>
#include <cstddef>

#define NN 10
#define NB 512
#define NP 1152
#define CI 8
#define CO 16
#define BLOCK 1024    // 16 waves -> 4 waves/SIMD minimum -> hard 128-VGPR cap, 1 block/CU
#define BT 4          // batches per block (W fragment reused 4x from registers)
#define PS 128        // p-slots = BLOCK/8 (8 threads per p, each owns an o-pair)
#define PT 9          // NP / PS
#define NW 16         // waves per block

typedef float v2f __attribute__((ext_vector_type(2)));
typedef float v4f __attribute__((ext_vector_type(4)));

__global__ __launch_bounds__(BLOCK)
void caps_kernel(const float* __restrict__ x, const float* __restrict__ W,
                 float* __restrict__ out) {
  __shared__ float mred[BT][NW];          // per-wave max partials
  __shared__ float sred[NW][BT][CO];      // per-wave s partials
  __shared__ float zred[BT][NW];          // per-wave Z partials
  __shared__ float vbuf[BT][CO];          // broadcast v

  const int tid  = threadIdx.x;
  const int lane = tid & 63;
  const int wid  = tid >> 6;
  const int op   = tid & 7;          // o-pair index: owns o = 2*op, 2*op+1
  const int ps   = tid >> 3;         // p-slot 0..127 ; p = ps + 128*k

  // grid order: (n-pair, b-group, n-within) -> concurrent window shares 2 n's of W
  const int bid = blockIdx.x;
  const int n   = (bid >> 8) * 2 + (bid & 1);
  const int b0  = ((bid >> 1) & 127) * BT;

  // ---------------- u-build: u[b][k] = o-pair of x[b,p,:] @ W[n,p,:,:] ----------------
  v2f u[BT][PT];
  const float* Wp = W + ((size_t)n * NP + ps) * (CI * CO) + (op << 1);
  const float* xp = x + ((size_t)b0 * NP + ps) * CI;

#pragma unroll
  for (int k = 0; k < PT; ++k) {
    const float* wr = Wp + (size_t)k * (PS * CI * CO);
    v2f wv[CI];
#pragma unroll
    for (int i = 0; i < CI; ++i) wv[i] = *(const v2f*)(wr + i * CO);
#pragma unroll
    for (int b = 0; b < BT; ++b) {
      const float* xr = xp + (size_t)(b * NP + k * PS) * CI;
      float xi[CI];
      *(v4f*)&xi[0] = *(const v4f*)(xr);
      *(v4f*)&xi[4] = *(const v4f*)(xr + 4);
      v2f a = xi[0] * wv[0];
#pragma unroll
      for (int i = 1; i < CI; ++i) a += xi[i] * wv[i];
      u[b][k] = a;
    }
  }

  v2f vsum[BT];   // running sum of v's == the (o-uniform) routing logit generator
  v2f vvb[BT];
  float mm[BT];

  // ---------------- iter 0: c uniform -> s = mean_p u ----------------
#pragma unroll
  for (int b = 0; b < BT; ++b) {
    v2f s2 = u[b][0];
#pragma unroll
    for (int k = 1; k < PT; ++k) s2 += u[b][k];
#pragma unroll
    for (int s = 8; s <= 32; s <<= 1) {
      s2.x += __shfl_xor(s2.x, s);
      s2.y += __shfl_xor(s2.y, s);
    }
    if (lane < 8) *(v2f*)&sred[wid][b][op << 1] = s2;
  }
  __syncthreads();
  if (tid < 64) {
    const int b = tid >> 4, o = tid & 15;
    float s = 0.f;
#pragma unroll
    for (int w = 0; w < NW; ++w) s += sred[w][b][o];
    s *= (1.f / (float)NP);
    float sq = s * s;
#pragma unroll
    for (int m2 = 1; m2 <= 8; m2 <<= 1) sq += __shfl_xor(sq, m2);
    vbuf[b][o] = s * (sqrtf(sq) / (1.f + sq));
  }
  __syncthreads();
#pragma unroll
  for (int b = 0; b < BT; ++b) {
    vvb[b] = *(const v2f*)&vbuf[b][op << 1];
    vsum[b] = vvb[b];
  }

  // ---------------- iters 1,2: logits = u . vsum ----------------
#pragma unroll 1
  for (int it = 1; it < 3; ++it) {
    // pass A: block max of d = u.vsum over p
#pragma unroll
    for (int b = 0; b < BT; ++b) {
      float m = -1e30f;
#pragma unroll
      for (int k = 0; k < PT; ++k) {
        const v2f t = u[b][k] * vsum[b];
        float d = t.x + t.y;
        d += __shfl_xor(d, 1);
        d += __shfl_xor(d, 2);
        d += __shfl_xor(d, 4);
        m = fmaxf(m, d);
      }
#pragma unroll
      for (int s = 8; s <= 32; s <<= 1) m = fmaxf(m, __shfl_xor(m, s));
      if (lane == 0) mred[b][wid] = m;
    }
    __syncthreads();
#pragma unroll
    for (int b = 0; b < BT; ++b) {
      const v4f* mr = (const v4f*)&mred[b][0];
      v4f m4 = mr[0];
      m4 = (v4f){fmaxf(m4.x, mr[1].x), fmaxf(m4.y, mr[1].y), fmaxf(m4.z, mr[1].z), fmaxf(m4.w, mr[1].w)};
      m4 = (v4f){fmaxf(m4.x, mr[2].x), fmaxf(m4.y, mr[2].y), fmaxf(m4.z, mr[2].z), fmaxf(m4.w, mr[2].w)};
      m4 = (v4f){fmaxf(m4.x, mr[3].x), fmaxf(m4.y, mr[3].y), fmaxf(m4.z, mr[3].z), fmaxf(m4.w, mr[3].w)};
      mm[b] = fmaxf(fmaxf(m4.x, m4.y), fmaxf(m4.z, m4.w));
    }

    // pass B: S = sum_p e*u, Z = sum_p e, e = exp(d - m)
#pragma unroll
    for (int b = 0; b < BT; ++b) {
      v2f s2 = (v2f){0.f, 0.f};
      float z = 0.f;
#pragma unroll
      for (int k = 0; k < PT; ++k) {
        const v2f t = u[b][k] * vsum[b];
        float d = t.x + t.y;
        d += __shfl_xor(d, 1);
        d += __shfl_xor(d, 2);
        d += __shfl_xor(d, 4);
        const float e = __expf(d - mm[b]);
        z += e;
        s2 += e * u[b][k];
      }
#pragma unroll
      for (int s = 8; s <= 32; s <<= 1) {
        s2.x += __shfl_xor(s2.x, s);
        s2.y += __shfl_xor(s2.y, s);
        z    += __shfl_xor(z, s);
      }
      if (lane < 8)  *(v2f*)&sred[wid][b][op << 1] = s2;
      if (lane == 0) zred[b][wid] = z;
    }
    __syncthreads();

    // finalize: 64 threads -> s = S/Z, squash
    if (tid < 64) {
      const int b = tid >> 4, o = tid & 15;
      float s = 0.f, Z = 0.f;
#pragma unroll
      for (int w = 0; w < NW; ++w) s += sred[w][b][o];
      {
        const v4f* zr = (const v4f*)&zred[b][0];
        const v4f z4 = zr[0] + zr[1] + zr[2] + zr[3];
        Z = z4.x + z4.y + z4.z + z4.w;
      }
      s /= Z;
      float sq = s * s;
#pragma unroll
      for (int m2 = 1; m2 <= 8; m2 <<= 1) sq += __shfl_xor(sq, m2);
      const float vj = s * (sqrtf(sq) / (1.f + sq));
      if (it == 2) out[((size_t)n * NB + b0 + b) * CO + o] = vj;
      else         vbuf[b][o] = vj;
    }
    if (it < 2) {
      __syncthreads();
#pragma unroll
      for (int b = 0; b < BT; ++b) {
        vvb[b] = *(const v2f*)&vbuf[b][op << 1];
        vsum[b] += vvb[b];
      }
    }
  }
}

extern "C" void kernel_launch(void* const* d_in, const int* in_sizes, int n_in,
                              void* d_out, int out_size, void* d_ws, size_t ws_size,
                              hipStream_t stream) {
  const float* x = (const float*)d_in[0];
  const float* W = (const float*)d_in[1];
  float* out     = (float*)d_out;
  (void)in_sizes; (void)n_in; (void)out_size; (void)d_ws; (void)ws_size;
  const int grid = NN * (NB / BT);   // 1280 blocks: (n-pair, b-group, n-within)
  caps_kernel<<<grid, BLOCK, 0, stream>>>(x, W, out);
}

// Round 5
// 1052.435 us; speedup vs baseline: 1.1325x; 1.1325x over previous
//
#include <hip/hip_runtime.h>
#include <cstddef>

#define NN 10
#define NB 512
#define NP 1152
#define CI 8
#define CO 16
#define BLOCK 1024    // 16 waves; launch_bounds(…,4) -> 1 block/CU, 128-VGPR budget
#define BT 4          // batches per block (W fragment reused 4x from registers)
#define PS 128        // p-slots = BLOCK/8 (8 threads per p, each owns an o-pair)
#define PT 9          // NP / PS
#define NW 16         // waves per block

typedef float v2f __attribute__((ext_vector_type(2)));
typedef float v4f __attribute__((ext_vector_type(4)));

__global__ __launch_bounds__(BLOCK, 4)
void caps_kernel(const float* __restrict__ x, const float* __restrict__ W,
                 float* __restrict__ out) {
  __shared__ float sred[NW][BT][CO];      // per-wave s partials (4 KB)
  __shared__ float zred[BT][NW];          // per-wave Z partials
  __shared__ float vbuf[BT][CO];          // broadcast v

  const int tid  = threadIdx.x;
  const int lane = tid & 63;
  const int wid  = tid >> 6;
  const int op   = tid & 7;          // o-pair index: owns o = 2*op, 2*op+1
  const int ps   = tid >> 3;         // p-slot 0..127 ; p = ps + 128*k

  // grid order: (n-pair, b-group, n-within) -> concurrent window shares 2 n's of W
  const int bid = blockIdx.x;
  const int n   = (bid >> 8) * 2 + (bid & 1);
  const int b0  = ((bid >> 1) & 127) * BT;

  // ---------------- u-build: u[b][k] = o-pair of x[b,p,:] @ W[n,p,:,:] ----------------
  v2f u[BT][PT];
  const float* Wp = W + ((size_t)n * NP + ps) * (CI * CO) + (op << 1);
  const float* xp = x + ((size_t)b0 * NP + ps) * CI;

#pragma unroll
  for (int k = 0; k < PT; ++k) {
    const float* wr = Wp + (size_t)k * (PS * CI * CO);
    v2f wv[CI];
#pragma unroll
    for (int i = 0; i < CI; ++i) wv[i] = *(const v2f*)(wr + i * CO);
#pragma unroll
    for (int b = 0; b < BT; ++b) {
      const float* xr = xp + (size_t)(b * NP + k * PS) * CI;
      float xi[CI];
      *(v4f*)&xi[0] = *(const v4f*)(xr);
      *(v4f*)&xi[4] = *(const v4f*)(xr + 4);
      v2f a = xi[0] * wv[0];
#pragma unroll
      for (int i = 1; i < CI; ++i) a += xi[i] * wv[i];
      u[b][k] = a;
    }
  }

  v2f vsum[BT];   // running sum of v's == the (o-uniform) routing logit generator

  // ---------------- iter 0: c uniform -> s = mean_p u ----------------
#pragma unroll
  for (int b = 0; b < BT; ++b) {
    v2f s2 = u[b][0];
#pragma unroll
    for (int k = 1; k < PT; ++k) s2 += u[b][k];
#pragma unroll
    for (int s = 8; s <= 32; s <<= 1) {
      s2.x += __shfl_xor(s2.x, s);
      s2.y += __shfl_xor(s2.y, s);
    }
    if (lane < 8) *(v2f*)&sred[wid][b][op << 1] = s2;
  }
  __syncthreads();
  if (tid < 64) {
    const int b = tid >> 4, o = tid & 15;
    float s = 0.f;
#pragma unroll
    for (int w = 0; w < NW; ++w) s += sred[w][b][o];
    s *= (1.f / (float)NP);
    float sq = s * s;
#pragma unroll
    for (int m2 = 1; m2 <= 8; m2 <<= 1) sq += __shfl_xor(sq, m2);
    vbuf[b][o] = s * (sqrtf(sq) / (1.f + sq));
  }
  __syncthreads();
#pragma unroll
  for (int b = 0; b < BT; ++b) vsum[b] = *(const v2f*)&vbuf[b][op << 1];

  // ---------------- iters 1,2: c = softmax_p(u . vsum), no max-sub needed ----------------
  // |d| <= ||u_p|| * ||vsum|| <~ 45  ->  exp safely inside fp32 range.
#pragma unroll 1
  for (int it = 1; it < 3; ++it) {
#pragma unroll
    for (int b = 0; b < BT; ++b) {
      v2f s2 = (v2f){0.f, 0.f};
      float z = 0.f;
#pragma unroll
      for (int k = 0; k < PT; ++k) {
        const v2f t = u[b][k] * vsum[b];
        float d = t.x + t.y;
        d += __shfl_xor(d, 1);
        d += __shfl_xor(d, 2);
        d += __shfl_xor(d, 4);
        const float e = __expf(d);
        z += e;
        s2 += e * u[b][k];
      }
#pragma unroll
      for (int s = 8; s <= 32; s <<= 1) {
        s2.x += __shfl_xor(s2.x, s);
        s2.y += __shfl_xor(s2.y, s);
        z    += __shfl_xor(z, s);
      }
      if (lane < 8)  *(v2f*)&sred[wid][b][op << 1] = s2;
      if (lane == 0) zred[b][wid] = z;
    }
    __syncthreads();

    // finalize: 64 threads -> s = S/Z, squash
    if (tid < 64) {
      const int b = tid >> 4, o = tid & 15;
      float s = 0.f;
#pragma unroll
      for (int w = 0; w < NW; ++w) s += sred[w][b][o];
      float Z;
      {
        const v4f* zr = (const v4f*)&zred[b][0];
        const v4f z4 = zr[0] + zr[1] + zr[2] + zr[3];
        Z = (z4.x + z4.y) + (z4.z + z4.w);
      }
      s /= Z;
      float sq = s * s;
#pragma unroll
      for (int m2 = 1; m2 <= 8; m2 <<= 1) sq += __shfl_xor(sq, m2);
      const float vj = s * (sqrtf(sq) / (1.f + sq));
      if (it == 2) out[((size_t)n * NB + b0 + b) * CO + o] = vj;
      else         vbuf[b][o] = vj;
    }
    if (it < 2) {
      __syncthreads();
#pragma unroll
      for (int b = 0; b < BT; ++b) vsum[b] += *(const v2f*)&vbuf[b][op << 1];
    }
  }
}

extern "C" void kernel_launch(void* const* d_in, const int* in_sizes, int n_in,
                              void* d_out, int out_size, void* d_ws, size_t ws_size,
                              hipStream_t stream) {
  const float* x = (const float*)d_in[0];
  const float* W = (const float*)d_in[1];
  float* out     = (float*)d_out;
  (void)in_sizes; (void)n_in; (void)out_size; (void)d_ws; (void)ws_size;
  const int grid = NN * (NB / BT);   // 1280 blocks: (n-pair, b-group, n-within)
  caps_kernel<<<grid, BLOCK, 0, stream>>>(x, W, out);
}

// Round 9
// 951.670 us; speedup vs baseline: 1.2524x; 1.1059x over previous
//
#include <hip/hip_runtime.h>
#include <cstddef>

#define NN 10
#define NB 512
#define NP 1152
#define CI 8
#define CO 16
#define BLOCK 1024   // 16 waves, 1 block/CU (LDS-bound); live set designed < 64 VGPR
#define BT 2         // batches per block; u tile = BT*1152*16 fp32 = 147 KB LDS
#define PS 128       // p-slots (8 threads per p: each owns an o-pair)
#define PT 9         // NP / PS
#define NW 16

// LDS layout (floats)
#define U_FLOATS  (BT * NP * CO)                 // 36864
#define SRED_OFF  (U_FLOATS)                     // [NW][BT][CO] = 512
#define ZRED_OFF  (SRED_OFF + NW * BT * CO)      // [BT][NW] = 32
#define VBUF_OFF  (ZRED_OFF + BT * NW)           // [BT][CO] = 32
#define SMEM_FLOATS (VBUF_OFF + BT * CO)
#define SMEM_BYTES  (SMEM_FLOATS * 4)            // 149,888 B < 160 KiB

typedef float v2f __attribute__((ext_vector_type(2)));
typedef float v4f __attribute__((ext_vector_type(4)));

__global__ __launch_bounds__(BLOCK)
void caps_kernel(const float* __restrict__ x, const float* __restrict__ W,
                 float* __restrict__ out) {
  extern __shared__ float smem[];

  const int tid  = threadIdx.x;
  const int lane = tid & 63;
  const int wid  = tid >> 6;
  const int op   = tid & 7;       // o-pair: owns o = 2op, 2op+1
  const int ps   = tid >> 3;      // p-slot 0..127; p = ps + 128k

  const int b0 = blockIdx.x * BT; // 256 blocks cover B=512
  const float* xp = x + ((size_t)b0 * NP + ps) * CI;

#pragma unroll 1
  for (int n = 0; n < NN; ++n) {
    const float* Wp = W + ((size_t)n * NP + ps) * (CI * CO) + (op << 1);

    // ---------------- build u into LDS; accumulate iter-0 sum on the fly ----------------
    v2f s0[BT];
#pragma unroll
    for (int b = 0; b < BT; ++b) s0[b] = (v2f){0.f, 0.f};

#pragma unroll
    for (int k = 0; k < PT; ++k) {
      const float* wr = Wp + (size_t)k * (PS * CI * CO);
      v2f wv[CI];
#pragma unroll
      for (int i = 0; i < CI; ++i) wv[i] = *(const v2f*)(wr + i * CO);
#pragma unroll
      for (int b = 0; b < BT; ++b) {
        const float* xr = xp + (size_t)(b * NP + k * PS) * CI;
        float xi[CI];
        *(v4f*)&xi[0] = *(const v4f*)(xr);
        *(v4f*)&xi[4] = *(const v4f*)(xr + 4);
        v2f a = xi[0] * wv[0];
#pragma unroll
        for (int i = 1; i < CI; ++i) a += xi[i] * wv[i];
        // wave writes 8 p's x 64B = 512B contiguous -> conflict-free
        *(v2f*)&smem[(size_t)(b * NP + k * PS + ps) * CO + (op << 1)] = a;
        s0[b] += a;
      }
    }

    // iter-0 reduce: over ps within wave, then cross-wave via LDS
#pragma unroll
    for (int b = 0; b < BT; ++b) {
#pragma unroll
      for (int s = 8; s <= 32; s <<= 1) {
        s0[b].x += __shfl_xor(s0[b].x, s);
        s0[b].y += __shfl_xor(s0[b].y, s);
      }
      if (lane < 8) *(v2f*)&smem[SRED_OFF + (wid * BT + b) * CO + (op << 1)] = s0[b];
    }
    __syncthreads();

    if (tid < BT * CO) {  // 32 threads: b = tid>>4, o = tid&15
      const int b = tid >> 4, o = tid & 15;
      float s = 0.f;
#pragma unroll
      for (int w = 0; w < NW; ++w) s += smem[SRED_OFF + (w * BT + b) * CO + o];
      s *= (1.f / (float)NP);
      float sq = s * s;
#pragma unroll
      for (int m2 = 1; m2 <= 8; m2 <<= 1) sq += __shfl_xor(sq, m2);
      smem[VBUF_OFF + b * CO + o] = s * (sqrtf(sq) / (1.f + sq));
    }
    __syncthreads();

    v2f vsum[BT];
#pragma unroll
    for (int b = 0; b < BT; ++b) vsum[b] = *(const v2f*)&smem[VBUF_OFF + b * CO + (op << 1)];

    // ---------------- iters 1,2: c = softmax_p(u . vsum); no max-sub (|d| <~ 25) ----------------
#pragma unroll 1
    for (int it = 1; it < 3; ++it) {
#pragma unroll
      for (int b = 0; b < BT; ++b) {
        v2f s2 = (v2f){0.f, 0.f};
        float z = 0.f;
#pragma unroll
        for (int k = 0; k < PT; ++k) {
          const v2f u2 = *(const v2f*)&smem[(size_t)(b * NP + k * PS + ps) * CO + (op << 1)];
          const v2f t = u2 * vsum[b];
          float d = t.x + t.y;
          d += __shfl_xor(d, 1);
          d += __shfl_xor(d, 2);
          d += __shfl_xor(d, 4);
          const float e = __expf(d);
          z += e;
          s2 += e * u2;
        }
#pragma unroll
        for (int s = 8; s <= 32; s <<= 1) {
          s2.x += __shfl_xor(s2.x, s);
          s2.y += __shfl_xor(s2.y, s);
          z    += __shfl_xor(z, s);
        }
        if (lane < 8)  *(v2f*)&smem[SRED_OFF + (wid * BT + b) * CO + (op << 1)] = s2;
        if (lane == 0) smem[ZRED_OFF + b * NW + wid] = z;
      }
      __syncthreads();

      if (tid < BT * CO) {
        const int b = tid >> 4, o = tid & 15;
        float s = 0.f, Z = 0.f;
#pragma unroll
        for (int w = 0; w < NW; ++w) {
          s += smem[SRED_OFF + (w * BT + b) * CO + o];
          Z += smem[ZRED_OFF + b * NW + w];
        }
        s /= Z;
        float sq = s * s;
#pragma unroll
        for (int m2 = 1; m2 <= 8; m2 <<= 1) sq += __shfl_xor(sq, m2);
        const float vj = s * (sqrtf(sq) / (1.f + sq));
        if (it == 2) out[((size_t)n * NB + b0 + b) * CO + o] = vj;
        else         smem[VBUF_OFF + b * CO + o] = vj;
      }
      if (it < 2) {
        __syncthreads();
#pragma unroll
        for (int b = 0; b < BT; ++b) vsum[b] += *(const v2f*)&smem[VBUF_OFF + b * CO + (op << 1)];
      }
    }
    __syncthreads();  // u/sred reused next n; also protects the tid<32 out-path
  }
}

extern "C" void kernel_launch(void* const* d_in, const int* in_sizes, int n_in,
                              void* d_out, int out_size, void* d_ws, size_t ws_size,
                              hipStream_t stream) {
  const float* x = (const float*)d_in[0];
  const float* W = (const float*)d_in[1];
  float* out     = (float*)d_out;
  (void)in_sizes; (void)n_in; (void)out_size; (void)d_ws; (void)ws_size;

  hipFuncSetAttribute((const void*)caps_kernel,
                      hipFuncAttributeMaxDynamicSharedMemorySize, SMEM_BYTES);

  caps_kernel<<<NB / BT, BLOCK, SMEM_BYTES, stream>>>(x, W, out);
}

// Round 12
// 498.671 us; speedup vs baseline: 2.3901x; 1.9084x over previous
//
#include <hip/hip_runtime.h>
#include <cstddef>

#define NN 10
#define NB 512
#define NP 1152
#define CI 8
#define CO 16
#define BLOCK 1024   // 16 waves; 1 block/CU (LDS-bound); live set < 64 VGPR
#define BT 2         // batches per tile; u tile = BT*1152*16 fp32 = 147 KB LDS
#define PS 128       // p-slots (8 threads per p: each owns an o-pair)
#define PT 9         // NP / PS
#define NW 16
#define NTILES (NB / BT)   // 256 b-tiles, partitioned among same-n blocks

// LDS layout (floats)
#define U_FLOATS  (BT * NP * CO)                 // 36864
#define SRED_OFF  (U_FLOATS)                     // [NW][BT][CO] = 512
#define ZRED_OFF  (SRED_OFF + NW * BT * CO)      // [BT][NW] = 32
#define VBUF_OFF  (ZRED_OFF + BT * NW)           // [BT][CO] = 32
#define SMEM_FLOATS (VBUF_OFF + BT * CO)
#define SMEM_BYTES  (SMEM_FLOATS * 4)            // 149,888 B < 160 KiB

typedef float v2f __attribute__((ext_vector_type(2)));
typedef float v4f __attribute__((ext_vector_type(4)));

__global__ __launch_bounds__(BLOCK)
void caps_kernel(const float* __restrict__ x, const float* __restrict__ W,
                 float* __restrict__ out) {
  extern __shared__ float smem[];

  const int tid  = threadIdx.x;
  const int lane = tid & 63;
  const int wid  = tid >> 6;
  const int op   = tid & 7;       // o-pair: owns o = 2op, 2op+1
  const int ps   = tid >> 3;      // p-slot 0..127; p = ps + 128k

  // 256 blocks = 6 n-groups of 26 + 4 n-groups of 25. Each block: ONE n, many b-tiles.
  // -> W[n] (589 KB) becomes L2-resident for this block after its first tile.
  const int bid = blockIdx.x;
  int n, g, G;
  if (bid < 6 * 26) { n = bid / 26; g = bid - n * 26; G = 26; }
  else { const int r = bid - 6 * 26; const int q = r / 25; n = 6 + q; g = r - q * 25; G = 25; }

  const float* Wp = W + ((size_t)n * NP + ps) * (CI * CO) + (op << 1);

#pragma unroll 1
  for (int t = g; t < NTILES; t += G) {
    const int b0 = t * BT;
    const float* xp = x + ((size_t)b0 * NP + ps) * CI;

    // ---------------- build u into LDS; accumulate iter-0 sum on the fly ----------------
    v2f s0[BT];
#pragma unroll
    for (int b = 0; b < BT; ++b) s0[b] = (v2f){0.f, 0.f};

#pragma unroll
    for (int k = 0; k < PT; ++k) {
      const float* wr = Wp + (size_t)k * (PS * CI * CO);
      v2f wv[CI];
#pragma unroll
      for (int i = 0; i < CI; ++i) wv[i] = *(const v2f*)(wr + i * CO);
#pragma unroll
      for (int b = 0; b < BT; ++b) {
        const float* xr = xp + (size_t)(b * NP + k * PS) * CI;
        float xi[CI];
        *(v4f*)&xi[0] = *(const v4f*)(xr);
        *(v4f*)&xi[4] = *(const v4f*)(xr + 4);
        v2f a = xi[0] * wv[0];
#pragma unroll
        for (int i = 1; i < CI; ++i) a += xi[i] * wv[i];
        // wave writes 8 p's x 64B = 512B contiguous -> conflict-free
        *(v2f*)&smem[(size_t)(b * NP + k * PS + ps) * CO + (op << 1)] = a;
        s0[b] += a;
      }
    }

    // iter-0 reduce: over ps within wave, then cross-wave via LDS
#pragma unroll
    for (int b = 0; b < BT; ++b) {
#pragma unroll
      for (int s = 8; s <= 32; s <<= 1) {
        s0[b].x += __shfl_xor(s0[b].x, s);
        s0[b].y += __shfl_xor(s0[b].y, s);
      }
      if (lane < 8) *(v2f*)&smem[SRED_OFF + (wid * BT + b) * CO + (op << 1)] = s0[b];
    }
    __syncthreads();

    if (tid < BT * CO) {  // 32 threads: b = tid>>4, o = tid&15
      const int b = tid >> 4, o = tid & 15;
      float s = 0.f;
#pragma unroll
      for (int w = 0; w < NW; ++w) s += smem[SRED_OFF + (w * BT + b) * CO + o];
      s *= (1.f / (float)NP);
      float sq = s * s;
#pragma unroll
      for (int m2 = 1; m2 <= 8; m2 <<= 1) sq += __shfl_xor(sq, m2);
      smem[VBUF_OFF + b * CO + o] = s * (sqrtf(sq) / (1.f + sq));
    }
    __syncthreads();

    v2f vsum[BT];
#pragma unroll
    for (int b = 0; b < BT; ++b) vsum[b] = *(const v2f*)&smem[VBUF_OFF + b * CO + (op << 1)];

    // ---------------- iters 1,2: c = softmax_p(u . vsum); no max-sub (|d| <~ 25) ----------------
#pragma unroll 1
    for (int it = 1; it < 3; ++it) {
#pragma unroll
      for (int b = 0; b < BT; ++b) {
        v2f s2 = (v2f){0.f, 0.f};
        float z = 0.f;
#pragma unroll
        for (int k = 0; k < PT; ++k) {
          const v2f u2 = *(const v2f*)&smem[(size_t)(b * NP + k * PS + ps) * CO + (op << 1)];
          const v2f tt = u2 * vsum[b];
          float d = tt.x + tt.y;
          d += __shfl_xor(d, 1);
          d += __shfl_xor(d, 2);
          d += __shfl_xor(d, 4);
          const float e = __expf(d);
          z += e;
          s2 += e * u2;
        }
#pragma unroll
        for (int s = 8; s <= 32; s <<= 1) {
          s2.x += __shfl_xor(s2.x, s);
          s2.y += __shfl_xor(s2.y, s);
          z    += __shfl_xor(z, s);
        }
        if (lane < 8)  *(v2f*)&smem[SRED_OFF + (wid * BT + b) * CO + (op << 1)] = s2;
        if (lane == 0) smem[ZRED_OFF + b * NW + wid] = z;
      }
      __syncthreads();

      if (tid < BT * CO) {
        const int b = tid >> 4, o = tid & 15;
        float s = 0.f, Z = 0.f;
#pragma unroll
        for (int w = 0; w < NW; ++w) {
          s += smem[SRED_OFF + (w * BT + b) * CO + o];
          Z += smem[ZRED_OFF + b * NW + w];
        }
        s /= Z;
        float sq = s * s;
#pragma unroll
        for (int m2 = 1; m2 <= 8; m2 <<= 1) sq += __shfl_xor(sq, m2);
        const float vj = s * (sqrtf(sq) / (1.f + sq));
        if (it == 2) out[((size_t)n * NB + b0 + b) * CO + o] = vj;
        else         smem[VBUF_OFF + b * CO + o] = vj;
      }
      if (it < 2) {
        __syncthreads();
#pragma unroll
        for (int b = 0; b < BT; ++b) vsum[b] += *(const v2f*)&smem[VBUF_OFF + b * CO + (op << 1)];
      }
    }
    __syncthreads();  // u/sred reused next tile; also protects the tid<32 out-path
  }
}

extern "C" void kernel_launch(void* const* d_in, const int* in_sizes, int n_in,
                              void* d_out, int out_size, void* d_ws, size_t ws_size,
                              hipStream_t stream) {
  const float* x = (const float*)d_in[0];
  const float* W = (const float*)d_in[1];
  float* out     = (float*)d_out;
  (void)in_sizes; (void)n_in; (void)out_size; (void)d_ws; (void)ws_size;

  hipFuncSetAttribute((const void*)caps_kernel,
                      hipFuncAttributeMaxDynamicSharedMemorySize, SMEM_BYTES);

  caps_kernel<<<256, BLOCK, SMEM_BYTES, stream>>>(x, W, out);
}